// Round 9
// baseline (377.000 us; speedup 1.0000x reference)
//
#include <hip/hip_runtime.h>
#include <cmath>

#define B_ 32
#define S_ 1024
#define D_ 256
#define K_ 1024
#define N_ (B_*S_)

// ---- output layout (float elements) ----
#define O_Q     0
#define O_LOSS  8388608
#define O_PERP  8388609
#define O_IDX   8388610
#define O_NW    8421378
#define O_NEW   8683522
#define O_NCS   8945666

// ---- workspace layout (bytes) ----
#define OFF_FH    0ull          // N*256*2 = 16777216 (f16 feats)
#define OFF_WH    16777216ull   // K*256*2 = 524288  (f16 weights)
#define OFF_BW    17301504ull   // K*8
#define OFF_BWF   17309696ull   // K*4
#define OFF_SAMP  17313792ull   // N*8
#define OFF_IDXF  17575936ull   // N*4
#define OFF_ENC   17707008ull   // N*4
#define OFF_CNT   17838080ull   // K*4 (zeroed by k_pre tail block)
#define OFF_LOSSP 17973312ull   // N*8
#define OFF_COFF  18235456ull   // K*4  CSR offsets
#define OFF_ROWL  18243648ull   // N*4  CSR row list
#define OFF_MUIV  18374720ull   // N*8  (f32 mu, f32 inv) per row
#define OFF_AR    18636864ull   // N*8  f64 ||f||^2 per row
#define OFF_NTOT  18899008ull   // 8    f64 ntot

#define MARGIN 4e-5f

typedef _Float16 f16x8 __attribute__((ext_vector_type(8)));
typedef _Float16 f16x4 __attribute__((ext_vector_type(4)));
typedef float    f32x4 __attribute__((ext_vector_type(4)));

// offset arg must be a literal at Sema time -> fold k-offset into gp instead.
#define GL16(gp, lp) __builtin_amdgcn_global_load_lds( \
    (const __attribute__((address_space(1))) unsigned int*)(const void*)(gp), \
    (__attribute__((address_space(3))) unsigned int*)(void*)(lp), 16, 0, 0)

// ---------------- fused: LN -> f16 feats + (mu,inv,A) | ||w||^2 + f16 w ----
// f32 LN math; stores per-row (mu, inv) f32 and A=||f||^2 (f64-accumulated)
// so phase2 skips the stat reduce chains. Tail block zeroes cnt.
__global__ void k_pre(const float* __restrict__ x, const float* __restrict__ gam,
                      const float* __restrict__ bet, _Float16* __restrict__ fh,
                      const float* __restrict__ w, double* __restrict__ Bw,
                      float* __restrict__ Bwf, _Float16* __restrict__ wh,
                      float2* __restrict__ muiv, double* __restrict__ Ar,
                      unsigned* __restrict__ cnt) {
    int lane = threadIdx.x & 63, wv = threadIdx.x >> 6;
    if (blockIdx.x < N_ / 4) {
        int n = blockIdx.x * 4 + wv;
        const float4 xv = ((const float4*)(x + (size_t)n * D_))[lane];
        const float4 gv = ((const float4*)gam)[lane];
        const float4 bv = ((const float4*)bet)[lane];
        float s = xv.x + xv.y + xv.z + xv.w;
        for (int m = 32; m > 0; m >>= 1) s += __shfl_xor(s, m, 64);
        float mu = s * (1.0f / 256.0f);
        float c0 = xv.x - mu, c1 = xv.y - mu, c2 = xv.z - mu, c3 = xv.w - mu;
        float vs = c0 * c0 + c1 * c1 + c2 * c2 + c3 * c3;
        for (int m = 32; m > 0; m >>= 1) vs += __shfl_xor(vs, m, 64);
        float inv = 1.0f / sqrtf(vs * (1.0f / 256.0f) + 1e-5f);
        float f0 = c0 * inv * gv.x + bv.x;
        float f1 = c1 * inv * gv.y + bv.y;
        float f2 = c2 * inv * gv.z + bv.z;
        float f3 = c3 * inv * gv.w + bv.w;
        double a = (double)f0 * f0 + (double)f1 * f1
                 + (double)f2 * f2 + (double)f3 * f3;
        for (int m = 32; m > 0; m >>= 1) a += __shfl_xor(a, m, 64);
        f16x4 o;
        o[0] = (_Float16)f0; o[1] = (_Float16)f1;
        o[2] = (_Float16)f2; o[3] = (_Float16)f3;
        *(f16x4*)&fh[(size_t)n * D_ + lane * 4] = o;
        if (lane == 0) { muiv[n] = make_float2(mu, inv); Ar[n] = a; }
    } else if (blockIdx.x < N_ / 4 + K_ / 4) {
        int k = (blockIdx.x - N_ / 4) * 4 + wv;
        const float4 v = ((const float4*)(w + (size_t)k * D_))[lane];
        double s = (double)v.x * v.x + (double)v.y * v.y
                 + (double)v.z * v.z + (double)v.w * v.w;
        for (int m = 32; m > 0; m >>= 1) s += __shfl_xor(s, m, 64);
        f16x4 o;
        o[0] = (_Float16)v.x; o[1] = (_Float16)v.y;
        o[2] = (_Float16)v.z; o[3] = (_Float16)v.w;
        *(f16x4*)&wh[(size_t)k * D_ + lane * 4] = o;
        if (lane == 0) { Bw[k] = s; Bwf[k] = (float)s; }
    } else {
        // zero cnt (K u32)
        int t = threadIdx.x;
#pragma unroll
        for (int i = 0; i < 4; i++) cnt[t + i * 256] = 0u;
    }
}

// ---------------- Phase 1: f16 MFMA GEMM + fused top-2 (R4 winner) -------------
// 1024 blocks x 512 thr (8 waves). Block = 128 rows x 256 codes;
// wave (wr,wc) owns a 64x64 sub-tile; acc = 16 f32x4 = 64 regs/wave.
// OPERAND-SWAPPED MFMA (D.col=row n, D.row=code): lane holds 16 code
// candidates in-register -> top-2 = in-reg scan + 2 shuffle rounds.
// Schedule: 3-buffer LDS rotation, ONE raw s_barrier per K-step, counted
// s_waitcnt vmcnt(3) (never drain to 0 in the main loop).
__launch_bounds__(512, 4)
__global__ void k_phase1(const _Float16* __restrict__ fh, const _Float16* __restrict__ wh,
                         const float* __restrict__ Bwf, float* __restrict__ pq) {
    __shared__ __align__(16) _Float16 sA[3][128][32];   // 24 KB
    __shared__ __align__(16) _Float16 sB[3][256][32];   // 48 KB

    const int tid = threadIdx.x;
    const int lane = tid & 63;
    const int w = tid >> 6;        // wave 0..7
    const int wr = w >> 2;         // row half 0..1 (64 rows)
    const int wc = w & 3;          // col quarter 0..3 (64 codes)
    const int l15 = lane & 15;
    const int g = lane >> 4;       // 0..3
    const int id = blockIdx.x;
    const int grp = (id & 7) * 32 + (id >> 5);       // 0..255
    const int chunk = (id >> 3) & 3;
    const int row0 = grp * 128;
    const int c0 = chunk * 256;

    // staging: 24 GL16 loads cover A(8KB)+B(16KB) per epoch; wave w owns
    // loads li = 3w..3w+2. li<8 -> A rows li*16, li>=8 -> B rows (li-8)*16.
    const int srow = lane >> 2;
    const int scol = (lane & 3) * 8;
    const _Float16* gp[3];
    int lrow[3]; int isA[3];
#pragma unroll
    for (int j = 0; j < 3; j++) {
        int li = w * 3 + j;
        if (li < 8) {
            isA[j] = 1; lrow[j] = li * 16;
            gp[j] = fh + (size_t)(row0 + li * 16 + srow) * 256 + scol;
        } else {
            isA[j] = 0; lrow[j] = (li - 8) * 16;
            gp[j] = wh + (size_t)(c0 + (li - 8) * 16 + srow) * 256 + scol;
        }
    }

    // acc[cb][rb]: cb = code block (16 codes), rb = row block (16 rows)
    f32x4 acc[4][4];
#pragma unroll
    for (int a = 0; a < 4; a++)
#pragma unroll
        for (int b = 0; b < 4; b++) acc[a][b] = (f32x4){0.f, 0.f, 0.f, 0.f};

#define STAGE(bi, kk) do { \
    const int eoff_ = (kk) * 32; \
    _Pragma("unroll") \
    for (int j_ = 0; j_ < 3; j_++) { \
        if (isA[j_]) GL16(gp[j_] + eoff_, &sA[bi][lrow[j_]][0]); \
        else         GL16(gp[j_] + eoff_, &sB[bi][lrow[j_]][0]); \
    } \
} while (0)

    // prologue: stage k-steps 0 and 1; wait only this wave's oldest 3 (buf0).
    STAGE(0, 0);
    STAGE(1, 1);
    asm volatile("s_waitcnt vmcnt(3)" ::: "memory");
    __builtin_amdgcn_s_barrier();
    __builtin_amdgcn_sched_barrier(0);

#pragma unroll
    for (int ks = 0; ks < 8; ks++) {
        const int cur = ks % 3;
        if (ks < 6) STAGE((ks + 2) % 3, ks + 2);   // 3 new loads in flight/wave

        f16x8 cfr[4];   // code fragments (A-operand after swap)
#pragma unroll
        for (int cb = 0; cb < 4; cb++)
            cfr[cb] = *(const f16x8*)&sB[cur][wc * 64 + cb * 16 + l15][g * 8];
        __builtin_amdgcn_s_setprio(1);
#pragma unroll
        for (int rb = 0; rb < 4; rb++) {
            f16x8 rf = *(const f16x8*)&sA[cur][wr * 64 + rb * 16 + l15][g * 8];
#pragma unroll
            for (int cb = 0; cb < 4; cb++)
                acc[cb][rb] = __builtin_amdgcn_mfma_f32_16x16x32_f16(
                    cfr[cb], rf, acc[cb][rb], 0, 0, 0);
        }
        __builtin_amdgcn_s_setprio(0);
        __builtin_amdgcn_sched_barrier(0);

        // end of epoch: wait for NEXT buffer's loads only (issued last epoch),
        // leaving this epoch's 3 prefetches in flight across the barrier.
        if (ks < 6)       asm volatile("s_waitcnt vmcnt(3)" ::: "memory");
        else if (ks == 6) asm volatile("s_waitcnt vmcnt(0)" ::: "memory");
        if (ks < 7) {
            __builtin_amdgcn_s_barrier();
            __builtin_amdgcn_sched_barrier(0);
        }
    }
#undef STAGE
    __syncthreads();

    // per-lane ||w||^2 for its 16 codes: code = c0 + wc*64 + cb*16 + g*4 + r
    float bwv[4][4];
#pragma unroll
    for (int cb = 0; cb < 4; cb++)
#pragma unroll
        for (int r = 0; r < 4; r++)
            bwv[cb][r] = Bwf[c0 + wc * 64 + cb * 16 + g * 4 + r];

    // red: 128 rows x 4 wc-quadrant triples (m1,m2,c1) = 6 KB in sA[0]
    float* red = (float*)&sA[0][0][0];
#pragma unroll
    for (int rb = 0; rb < 4; rb++) {
        float m1 = 3e38f, m2 = 3e38f; int c1 = 0x7fffffff;
#pragma unroll
        for (int cb = 0; cb < 4; cb++) {
#pragma unroll
            for (int r = 0; r < 4; r++) {
                float sv = fmaf(-2.0f, acc[cb][rb][r], bwv[cb][r]);
                int c = c0 + wc * 64 + cb * 16 + g * 4 + r;
                if (sv < m1 || (sv == m1 && c < c1)) { m2 = m1; m1 = sv; c1 = c; }
                else if (sv < m2) m2 = sv;
            }
        }
        // reduce across the 4 g-groups (lanes stride 16)
#pragma unroll
        for (int msk = 16; msk <= 32; msk <<= 1) {
            float om1 = __shfl_xor(m1, msk, 64);
            float om2 = __shfl_xor(m2, msk, 64);
            int   oc  = __shfl_xor(c1, msk, 64);
            if (om1 < m1 || (om1 == m1 && oc < c1)) {
                m2 = (m1 < om2) ? m1 : om2; m1 = om1; c1 = oc;
            } else {
                m2 = (om1 < m2) ? om1 : m2;
            }
        }
        if (lane < 16) {
            int rl = wr * 64 + rb * 16 + l15;
            int base = (rl * 4 + wc) * 3;
            red[base] = m1; red[base + 1] = m2; ((int*)red)[base + 2] = c1;
        }
    }
    __syncthreads();
    if (tid < 128) {
        float M1 = 3e38f, M2 = 3e38f; int C1 = 0x7fffffff;
        for (int q = 0; q < 4; q++) {
            int base = (tid * 4 + q) * 3;
            float m1 = red[base], m2 = red[base + 1]; int c = ((int*)red)[base + 2];
            if (m1 < M1 || (m1 == M1 && c < C1)) {
                M2 = (M1 < m2) ? M1 : m2; M1 = m1; C1 = c;
            } else {
                M2 = (m1 < M2) ? m1 : M2;
            }
        }
        pq[chunk * N_ + row0 + tid] = M1;
        pq[4 * N_ + chunk * N_ + row0 + tid] = M2;
        ((int*)pq)[8 * N_ + chunk * N_ + row0 + tid] = C1;
    }
}

// ---------------- Phase 2: merge partials + exact verify + INLINE slow path ----
// Wave-uniform branch per row: fast rows do one exact f64 dot (C1); ambiguous
// rows (gap <= MARGIN) do the full 1024-code exact scan inline, lanes-over-codes
// (lane owns 16 ascending codes; f64 feats staged in wave-private LDS, no
// barrier needed). Replaces the separate k_slow dispatch.
__launch_bounds__(256)
__global__ void k_phase2(const float* __restrict__ x, const float* __restrict__ gam,
                         const float* __restrict__ bet, const float* __restrict__ w,
                         const double* __restrict__ Bw, const float* __restrict__ pq,
                         const float2* __restrict__ muiv, const double* __restrict__ Ar,
                         double* __restrict__ sampled, int* __restrict__ idxf) {
    __shared__ double sf[4][256];   // per-wave f64 feats (slow path only)
    int lane = threadIdx.x & 63, wv = threadIdx.x >> 6;
    int n = blockIdx.x * 4 + wv;
    const float* pm1 = pq;
    const float* pm2 = pq + 4 * N_;
    const int*   pc1 = (const int*)pq + 8 * N_;
    float M1 = 3e38f, M2 = 3e38f; int C1 = 0x7fffffff;
#pragma unroll
    for (int c = 0; c < 4; c++) {
        float m1 = pm1[c * N_ + n], m2 = pm2[c * N_ + n]; int cc = pc1[c * N_ + n];
        if (m1 < M1 || (m1 == M1 && cc < C1)) {
            M2 = (M1 < m2) ? M1 : m2; M1 = m1; C1 = cc;
        } else {
            M2 = (m1 < M2) ? m1 : M2;
        }
    }
    float2 mi = muiv[n];
    double mu = mi.x, inv = mi.y;
    double A = Ar[n];
    const float* row = x + (size_t)n * D_;

    if (M2 - M1 > MARGIN) {
        // fast: exact verify of the single winner
        const float* wr_ = w + (size_t)C1 * D_;
        double ss = 0.0;
#pragma unroll
        for (int i = 0; i < 4; i++) {
            int d = lane + 64 * i;
            double f = ((double)row[d] - mu) * inv * (double)gam[d] + (double)bet[d];
            ss += f * (double)wr_[d];
        }
        for (int m = 32; m > 0; m >>= 1) ss += __shfl_xor(ss, m, 64);
        if (lane == 0) { sampled[n] = (A + Bw[C1]) - 2.0 * ss; idxf[n] = C1; }
    } else {
        // slow: full exact scan (wave-uniform branch, wave-private LDS)
#pragma unroll
        for (int i = 0; i < 4; i++) {
            int d = lane + 64 * i;
            sf[wv][d] = ((double)row[d] - mu) * inv * (double)gam[d] + (double)bet[d];
        }
        // wave-private LDS: compiler inserts lgkmcnt before reads; no barrier.
        double bm = 1.0e300; int bc = 0x7fffffff;
        for (int k = 0; k < 16; k++) {
            int cc = lane * 16 + k;            // ascending per lane
            const float* wr = w + (size_t)cc * D_;
            double acc2 = 0.0;
#pragma unroll 8
            for (int d4 = 0; d4 < 64; d4++) {
                float4 w4 = *(const float4*)(wr + d4 * 4);
                acc2 += sf[wv][d4 * 4] * (double)w4.x + sf[wv][d4 * 4 + 1] * (double)w4.y
                      + sf[wv][d4 * 4 + 2] * (double)w4.z + sf[wv][d4 * 4 + 3] * (double)w4.w;
            }
            double dist = (A + Bw[cc]) - 2.0 * acc2;
            if (dist < bm) { bm = dist; bc = cc; }   // ascending => lowest idx on tie
        }
        for (int m = 32; m > 0; m >>= 1) {
            double om = __shfl_xor(bm, m, 64);
            int    oc = __shfl_xor(bc, m, 64);
            if (om < bm || (om == bm && oc < bc)) { bm = om; bc = oc; }
        }
        if (lane == 0) { sampled[n] = bm; idxf[n] = bc; }
    }
}

// ---------------- stable argsort via parallel ranking -------------
// rank_i = #{j: v_j < v_i} + #{j<i: v_j == v_i}  (== stable argsort position)
// NOTE: enc[base+rank] = idxf[i] with i ROW-LOCAL (no base) -- faithful
// reproduction of the reference's flat-index bug.
__launch_bounds__(256)
__global__ void k_rank(const double* __restrict__ sampled, const int* __restrict__ idxf,
                       int* __restrict__ enc) {
    __shared__ double val[1024];
    int b = blockIdx.x >> 2;            // batch row
    int q = blockIdx.x & 3;             // quarter of the row
    int t = threadIdx.x;
    size_t base = (size_t)b * S_;
#pragma unroll
    for (int e = 0; e < 4; e++)
        val[t + e * 256] = sampled[base + t + e * 256];
    __syncthreads();
    int i = q * 256 + t;                // row-local element index
    double vi = val[i];
    int rank = 0;
#pragma unroll 8
    for (int j = 0; j < 1024; j++) {
        double vj = val[j];
        rank += (vj < vi) || (vj == vi && j < i);
    }
    enc[base + rank] = idxf[i];         // faithful reference flat-index bug
}

// ---------------- gather: quantized out, idx out, counts, per-row loss -------------
__global__ void k_gather(const float* __restrict__ x, const float* __restrict__ w,
                         const int* __restrict__ enc, float* __restrict__ out,
                         unsigned* __restrict__ cnt, double* __restrict__ lossP) {
    int lane = threadIdx.x & 63, wv = threadIdx.x >> 6;
    int n = blockIdx.x * 4 + wv;
    int e = enc[n];
    const float4 q4 = ((const float4*)(w + (size_t)e * D_))[lane];
    const float4 x4 = ((const float4*)(x + (size_t)n * D_))[lane];
    ((float4*)(out + O_Q + (size_t)n * D_))[lane] = q4;
    double d0 = (double)q4.x - (double)x4.x;
    double d1 = (double)q4.y - (double)x4.y;
    double d2 = (double)q4.z - (double)x4.z;
    double d3 = (double)q4.w - (double)x4.w;
    double ls = d0 * d0 + d1 * d1 + d2 * d2 + d3 * d3;
    for (int m = 32; m > 0; m >>= 1) ls += __shfl_xor(ls, m, 64);
    if (lane == 0) {
        lossP[n] = ls;
        out[O_IDX + n] = (float)e;
        atomicAdd(&cnt[e], 1u);
    }
}

// ---------------- fused CSR build: scan -> coff; scatter via LDS cursors; ntot ----
// 1 block x 1024 thr. Saves a dispatch vs separate scan+scatter; within-code
// order is race-nondeterministic exactly like the old global-atomic scatter.
__launch_bounds__(1024)
__global__ void k_scansc(const unsigned* __restrict__ cnt, const float* __restrict__ ema_cs,
                         const int* __restrict__ enc, int* __restrict__ coff,
                         int* __restrict__ rowl, double* __restrict__ ntotP) {
    __shared__ int tmp[1024];
    __shared__ int curL[1024];
    __shared__ double redn[16];
    int t = threadIdx.x;
    int my = (int)cnt[t];
    tmp[t] = my;
    double part = (double)(0.99f * ema_cs[t] + 0.01f * (float)my);
    __syncthreads();
    for (int off = 1; off < 1024; off <<= 1) {
        int v = (t >= off) ? tmp[t - off] : 0;
        __syncthreads();
        tmp[t] += v;
        __syncthreads();
    }
    int excl = tmp[t] - my;
    coff[t] = excl;
    curL[t] = excl;
    for (int m = 32; m > 0; m >>= 1) part += __shfl_xor(part, m, 64);
    if ((t & 63) == 0) redn[t >> 6] = part;
    __syncthreads();
    if (t == 0) {
        double s = 0.0;
        for (int i = 0; i < 16; i++) s += redn[i];
        *ntotP = s;
    }
    // scatter: 32 strided passes over enc
    for (int it = 0; it < 32; it++) {
        int i = it * 1024 + t;
        int e = enc[i];
        int p = atomicAdd(&curL[e], 1);
        rowl[p] = i;
    }
}

// ---------------- post: dw via CSR row-list + new_weight + stats -------------
// ntot precomputed by k_scansc; 8-deep row pipeline for latency hiding.
__launch_bounds__(256)
__global__ void k_post(const unsigned* __restrict__ cnt, const float* __restrict__ ema_cs,
                       const double* __restrict__ lossP,
                       const int* __restrict__ coff, const int* __restrict__ rowl,
                       const float* __restrict__ x, const float* __restrict__ ema_w,
                       const double* __restrict__ ntotP, float* __restrict__ out) {
    __shared__ double redd[24];
    int tid = threadIdx.x;
    double ntot = *ntotP;

    if (blockIdx.x < K_) {
        int k = blockIdx.x;
        float cs0 = 0.99f * ema_cs[k] + 0.01f * (float)cnt[k];
        double csf = ((double)cs0 + 1e-5) / (ntot + 1024.0 * 1e-5) * ntot;
        int base = coff[k];
        int c = (int)cnt[k];
        float acc = 0.0f;
        int j = 0;
        for (; j + 8 <= c; j += 8) {
            int r[8];
#pragma unroll
            for (int u = 0; u < 8; u++) r[u] = rowl[base + j + u];
            float v[8];
#pragma unroll
            for (int u = 0; u < 8; u++) v[u] = x[(size_t)r[u] * D_ + tid];
#pragma unroll
            for (int u = 0; u < 8; u++) acc += v[u];
        }
        for (; j < c; j++) acc += x[(size_t)rowl[base + j] * D_ + tid];
        size_t idx = (size_t)k * D_ + tid;
        float ne = 0.99f * ema_w[idx] + 0.01f * acc;
        out[O_NEW + idx] = ne;
        out[O_NW + idx] = ne / (float)csf;
    } else {
        // stats block
        for (int i = tid; i < K_; i += 256) {
            float cs0 = 0.99f * ema_cs[i] + 0.01f * (float)cnt[i];
            double c2 = ((double)cs0 + 1e-5) / (ntot + 1024.0 * 1e-5) * ntot;
            out[O_NCS + i] = (float)c2;
        }
        double ent = 0.0;
        for (int i = tid; i < K_; i += 256) {
            double p = (double)cnt[i] / 32768.0;
            ent += -p * log(p + 1e-10);
        }
        for (int m = 32; m > 0; m >>= 1) ent += __shfl_xor(ent, m, 64);
        if ((tid & 63) == 0) redd[8 + (tid >> 6)] = ent;
        double ls = 0.0;
        for (int i = tid; i < N_; i += 256) ls += lossP[i];
        for (int m = 32; m > 0; m >>= 1) ls += __shfl_xor(ls, m, 64);
        if ((tid & 63) == 0) redd[16 + (tid >> 6)] = ls;
        __syncthreads();
        if (tid == 0) {
            double e = redd[8] + redd[9] + redd[10] + redd[11];
            double l = redd[16] + redd[17] + redd[18] + redd[19];
            out[O_PERP] = (float)exp(e);
            out[O_LOSS] = (float)(1.25 * l / 8388608.0);
        }
    }
}

extern "C" void kernel_launch(void* const* d_in, const int* in_sizes, int n_in,
                              void* d_out, int out_size, void* d_ws, size_t ws_size,
                              hipStream_t stream) {
    (void)in_sizes; (void)n_in; (void)out_size; (void)ws_size;
    const float* x      = (const float*)d_in[0];
    const float* w      = (const float*)d_in[1];
    const float* ema_w  = (const float*)d_in[2];
    const float* ema_cs = (const float*)d_in[3];
    const float* g      = (const float*)d_in[4];
    const float* bt     = (const float*)d_in[5];
    float* out = (float*)d_out;
    char* ws = (char*)d_ws;

    _Float16* fh = (_Float16*)(ws + OFF_FH);
    _Float16* wh = (_Float16*)(ws + OFF_WH);
    double* Bw   = (double*)(ws + OFF_BW);
    float*  Bwf  = (float*)(ws + OFF_BWF);
    double* samp = (double*)(ws + OFF_SAMP);
    int*    idxf = (int*)(ws + OFF_IDXF);
    int*    enc  = (int*)(ws + OFF_ENC);
    unsigned* cnt = (unsigned*)(ws + OFF_CNT);
    double* lossP = (double*)(ws + OFF_LOSSP);
    int*    coff  = (int*)(ws + OFF_COFF);
    int*    rowl  = (int*)(ws + OFF_ROWL);
    float2* muiv  = (float2*)(ws + OFF_MUIV);
    double* Ar    = (double*)(ws + OFF_AR);
    double* ntotP = (double*)(ws + OFF_NTOT);

    k_pre<<<N_ / 4 + K_ / 4 + 1, 256, 0, stream>>>(x, g, bt, fh, w, Bw, Bwf, wh,
                                                   muiv, Ar, cnt);
    k_phase1<<<1024, 512, 0, stream>>>(fh, wh, Bwf, out);  // partials in out-Q (dead region)
    k_phase2<<<N_ / 4, 256, 0, stream>>>(x, g, bt, w, Bw, out, muiv, Ar, samp, idxf);
    k_rank<<<B_ * 4, 256, 0, stream>>>(samp, idxf, enc);
    k_gather<<<N_ / 4, 256, 0, stream>>>(x, w, enc, out, cnt, lossP);
    k_scansc<<<1, 1024, 0, stream>>>(cnt, ema_cs, enc, coff, rowl, ntotP);
    k_post<<<K_ + 1, 256, 0, stream>>>(cnt, ema_cs, lossP, coff, rowl, x, ema_w,
                                       ntotP, out);
}

// Round 10
// 291.399 us; speedup vs baseline: 1.2938x; 1.2938x over previous
//
#include <hip/hip_runtime.h>
#include <cmath>

#define B_ 32
#define S_ 1024
#define D_ 256
#define K_ 1024
#define N_ (B_*S_)

// ---- output layout (float elements) ----
#define O_Q     0
#define O_LOSS  8388608
#define O_PERP  8388609
#define O_IDX   8388610
#define O_NW    8421378
#define O_NEW   8683522
#define O_NCS   8945666

// ---- workspace layout (bytes) ----
#define OFF_FH    0ull          // N*256*2 = 16777216 (f16 feats)
#define OFF_WH    16777216ull   // K*256*2 = 524288  (f16 weights)
#define OFF_BW    17301504ull   // K*8
#define OFF_BWF   17309696ull   // K*4
#define OFF_SAMP  17313792ull   // N*8
#define OFF_IDXF  17575936ull   // N*4
#define OFF_ENC   17707008ull   // N*4
#define OFF_CNT   17838080ull   // K*4 (zeroed by k_pre tail block)
#define OFF_SLOWC 17842176ull   // 64  (zeroed by k_pre tail block)
#define OFF_SLOWL 17842240ull   // N*4
#define OFF_LOSSP 17973312ull   // N*8
#define OFF_COFF  18235456ull   // K*4  CSR offsets
#define OFF_ROWL  18243648ull   // N*4  CSR row list
#define OFF_MUIV  18374720ull   // N*8  (f32 mu, f32 inv) per row
#define OFF_AR    18636864ull   // N*8  f64 ||f||^2 per row
#define OFF_NTOT  18899008ull   // 8    f64 ntot

#define MARGIN 4e-5f

typedef _Float16 f16x8 __attribute__((ext_vector_type(8)));
typedef _Float16 f16x4 __attribute__((ext_vector_type(4)));
typedef float    f32x4 __attribute__((ext_vector_type(4)));

// offset arg must be a literal at Sema time -> fold k-offset into gp instead.
#define GL16(gp, lp) __builtin_amdgcn_global_load_lds( \
    (const __attribute__((address_space(1))) unsigned int*)(const void*)(gp), \
    (__attribute__((address_space(3))) unsigned int*)(void*)(lp), 16, 0, 0)

// ---------------- fused: LN -> f16 feats + (mu,inv,A) | ||w||^2 + f16 w ----
// f32 LN math; stores per-row (mu, inv) f32 and A=||f||^2 (f64-accumulated)
// so phase2/slow skip the stat reduce chains. Tail block zeroes cnt+slowC.
__global__ void k_pre(const float* __restrict__ x, const float* __restrict__ gam,
                      const float* __restrict__ bet, _Float16* __restrict__ fh,
                      const float* __restrict__ w, double* __restrict__ Bw,
                      float* __restrict__ Bwf, _Float16* __restrict__ wh,
                      float2* __restrict__ muiv, double* __restrict__ Ar,
                      unsigned* __restrict__ cnt, unsigned* __restrict__ slowC) {
    int lane = threadIdx.x & 63, wv = threadIdx.x >> 6;
    if (blockIdx.x < N_ / 4) {
        int n = blockIdx.x * 4 + wv;
        const float4 xv = ((const float4*)(x + (size_t)n * D_))[lane];
        const float4 gv = ((const float4*)gam)[lane];
        const float4 bv = ((const float4*)bet)[lane];
        float s = xv.x + xv.y + xv.z + xv.w;
        for (int m = 32; m > 0; m >>= 1) s += __shfl_xor(s, m, 64);
        float mu = s * (1.0f / 256.0f);
        float c0 = xv.x - mu, c1 = xv.y - mu, c2 = xv.z - mu, c3 = xv.w - mu;
        float vs = c0 * c0 + c1 * c1 + c2 * c2 + c3 * c3;
        for (int m = 32; m > 0; m >>= 1) vs += __shfl_xor(vs, m, 64);
        float inv = 1.0f / sqrtf(vs * (1.0f / 256.0f) + 1e-5f);
        float f0 = c0 * inv * gv.x + bv.x;
        float f1 = c1 * inv * gv.y + bv.y;
        float f2 = c2 * inv * gv.z + bv.z;
        float f3 = c3 * inv * gv.w + bv.w;
        double a = (double)f0 * f0 + (double)f1 * f1
                 + (double)f2 * f2 + (double)f3 * f3;
        for (int m = 32; m > 0; m >>= 1) a += __shfl_xor(a, m, 64);
        f16x4 o;
        o[0] = (_Float16)f0; o[1] = (_Float16)f1;
        o[2] = (_Float16)f2; o[3] = (_Float16)f3;
        *(f16x4*)&fh[(size_t)n * D_ + lane * 4] = o;
        if (lane == 0) { muiv[n] = make_float2(mu, inv); Ar[n] = a; }
    } else if (blockIdx.x < N_ / 4 + K_ / 4) {
        int k = (blockIdx.x - N_ / 4) * 4 + wv;
        const float4 v = ((const float4*)(w + (size_t)k * D_))[lane];
        double s = (double)v.x * v.x + (double)v.y * v.y
                 + (double)v.z * v.z + (double)v.w * v.w;
        for (int m = 32; m > 0; m >>= 1) s += __shfl_xor(s, m, 64);
        f16x4 o;
        o[0] = (_Float16)v.x; o[1] = (_Float16)v.y;
        o[2] = (_Float16)v.z; o[3] = (_Float16)v.w;
        *(f16x4*)&wh[(size_t)k * D_ + lane * 4] = o;
        if (lane == 0) { Bw[k] = s; Bwf[k] = (float)s; }
    } else {
        // zero cnt (K u32) + slowC
        int t = threadIdx.x;
#pragma unroll
        for (int i = 0; i < 4; i++) cnt[t + i * 256] = 0u;
        if (t == 0) *slowC = 0u;
    }
}

// ---------------- Phase 1: f16 MFMA GEMM + fused top-2 (R4 winner) -------------
// 1024 blocks x 512 thr (8 waves). Block = 128 rows x 256 codes;
// wave (wr,wc) owns a 64x64 sub-tile; acc = 16 f32x4 = 64 regs/wave.
// OPERAND-SWAPPED MFMA (D.col=row n, D.row=code): lane holds 16 code
// candidates in-register -> top-2 = in-reg scan + 2 shuffle rounds.
// Schedule: 3-buffer LDS rotation, ONE raw s_barrier per K-step, counted
// s_waitcnt vmcnt(3) (never drain to 0 in the main loop).
__launch_bounds__(512, 4)
__global__ void k_phase1(const _Float16* __restrict__ fh, const _Float16* __restrict__ wh,
                         const float* __restrict__ Bwf, float* __restrict__ pq) {
    __shared__ __align__(16) _Float16 sA[3][128][32];   // 24 KB
    __shared__ __align__(16) _Float16 sB[3][256][32];   // 48 KB

    const int tid = threadIdx.x;
    const int lane = tid & 63;
    const int w = tid >> 6;        // wave 0..7
    const int wr = w >> 2;         // row half 0..1 (64 rows)
    const int wc = w & 3;          // col quarter 0..3 (64 codes)
    const int l15 = lane & 15;
    const int g = lane >> 4;       // 0..3
    const int id = blockIdx.x;
    const int grp = (id & 7) * 32 + (id >> 5);       // 0..255
    const int chunk = (id >> 3) & 3;
    const int row0 = grp * 128;
    const int c0 = chunk * 256;

    // staging: 24 GL16 loads cover A(8KB)+B(16KB) per epoch; wave w owns
    // loads li = 3w..3w+2. li<8 -> A rows li*16, li>=8 -> B rows (li-8)*16.
    const int srow = lane >> 2;
    const int scol = (lane & 3) * 8;
    const _Float16* gp[3];
    int lrow[3]; int isA[3];
#pragma unroll
    for (int j = 0; j < 3; j++) {
        int li = w * 3 + j;
        if (li < 8) {
            isA[j] = 1; lrow[j] = li * 16;
            gp[j] = fh + (size_t)(row0 + li * 16 + srow) * 256 + scol;
        } else {
            isA[j] = 0; lrow[j] = (li - 8) * 16;
            gp[j] = wh + (size_t)(c0 + (li - 8) * 16 + srow) * 256 + scol;
        }
    }

    // acc[cb][rb]: cb = code block (16 codes), rb = row block (16 rows)
    f32x4 acc[4][4];
#pragma unroll
    for (int a = 0; a < 4; a++)
#pragma unroll
        for (int b = 0; b < 4; b++) acc[a][b] = (f32x4){0.f, 0.f, 0.f, 0.f};

#define STAGE(bi, kk) do { \
    const int eoff_ = (kk) * 32; \
    _Pragma("unroll") \
    for (int j_ = 0; j_ < 3; j_++) { \
        if (isA[j_]) GL16(gp[j_] + eoff_, &sA[bi][lrow[j_]][0]); \
        else         GL16(gp[j_] + eoff_, &sB[bi][lrow[j_]][0]); \
    } \
} while (0)

    // prologue: stage k-steps 0 and 1; wait only this wave's oldest 3 (buf0).
    STAGE(0, 0);
    STAGE(1, 1);
    asm volatile("s_waitcnt vmcnt(3)" ::: "memory");
    __builtin_amdgcn_s_barrier();
    __builtin_amdgcn_sched_barrier(0);

#pragma unroll
    for (int ks = 0; ks < 8; ks++) {
        const int cur = ks % 3;
        if (ks < 6) STAGE((ks + 2) % 3, ks + 2);   // 3 new loads in flight/wave

        f16x8 cfr[4];   // code fragments (A-operand after swap)
#pragma unroll
        for (int cb = 0; cb < 4; cb++)
            cfr[cb] = *(const f16x8*)&sB[cur][wc * 64 + cb * 16 + l15][g * 8];
        __builtin_amdgcn_s_setprio(1);
#pragma unroll
        for (int rb = 0; rb < 4; rb++) {
            f16x8 rf = *(const f16x8*)&sA[cur][wr * 64 + rb * 16 + l15][g * 8];
#pragma unroll
            for (int cb = 0; cb < 4; cb++)
                acc[cb][rb] = __builtin_amdgcn_mfma_f32_16x16x32_f16(
                    cfr[cb], rf, acc[cb][rb], 0, 0, 0);
        }
        __builtin_amdgcn_s_setprio(0);
        __builtin_amdgcn_sched_barrier(0);

        // end of epoch: wait for NEXT buffer's loads only (issued last epoch),
        // leaving this epoch's 3 prefetches in flight across the barrier.
        if (ks < 6)       asm volatile("s_waitcnt vmcnt(3)" ::: "memory");
        else if (ks == 6) asm volatile("s_waitcnt vmcnt(0)" ::: "memory");
        if (ks < 7) {
            __builtin_amdgcn_s_barrier();
            __builtin_amdgcn_sched_barrier(0);
        }
    }
#undef STAGE
    __syncthreads();

    // per-lane ||w||^2 for its 16 codes: code = c0 + wc*64 + cb*16 + g*4 + r
    float bwv[4][4];
#pragma unroll
    for (int cb = 0; cb < 4; cb++)
#pragma unroll
        for (int r = 0; r < 4; r++)
            bwv[cb][r] = Bwf[c0 + wc * 64 + cb * 16 + g * 4 + r];

    // red: 128 rows x 4 wc-quadrant triples (m1,m2,c1) = 6 KB in sA[0]
    float* red = (float*)&sA[0][0][0];
#pragma unroll
    for (int rb = 0; rb < 4; rb++) {
        float m1 = 3e38f, m2 = 3e38f; int c1 = 0x7fffffff;
#pragma unroll
        for (int cb = 0; cb < 4; cb++) {
#pragma unroll
            for (int r = 0; r < 4; r++) {
                float sv = fmaf(-2.0f, acc[cb][rb][r], bwv[cb][r]);
                int c = c0 + wc * 64 + cb * 16 + g * 4 + r;
                if (sv < m1 || (sv == m1 && c < c1)) { m2 = m1; m1 = sv; c1 = c; }
                else if (sv < m2) m2 = sv;
            }
        }
        // reduce across the 4 g-groups (lanes stride 16)
#pragma unroll
        for (int msk = 16; msk <= 32; msk <<= 1) {
            float om1 = __shfl_xor(m1, msk, 64);
            float om2 = __shfl_xor(m2, msk, 64);
            int   oc  = __shfl_xor(c1, msk, 64);
            if (om1 < m1 || (om1 == m1 && oc < c1)) {
                m2 = (m1 < om2) ? m1 : om2; m1 = om1; c1 = oc;
            } else {
                m2 = (om1 < m2) ? om1 : m2;
            }
        }
        if (lane < 16) {
            int rl = wr * 64 + rb * 16 + l15;
            int base = (rl * 4 + wc) * 3;
            red[base] = m1; red[base + 1] = m2; ((int*)red)[base + 2] = c1;
        }
    }
    __syncthreads();
    if (tid < 128) {
        float M1 = 3e38f, M2 = 3e38f; int C1 = 0x7fffffff;
        for (int q = 0; q < 4; q++) {
            int base = (tid * 4 + q) * 3;
            float m1 = red[base], m2 = red[base + 1]; int c = ((int*)red)[base + 2];
            if (m1 < M1 || (m1 == M1 && c < C1)) {
                M2 = (M1 < m2) ? M1 : m2; M1 = m1; C1 = c;
            } else {
                M2 = (m1 < M2) ? m1 : M2;
            }
        }
        pq[chunk * N_ + row0 + tid] = M1;
        pq[4 * N_ + chunk * N_ + row0 + tid] = M2;
        ((int*)pq)[8 * N_ + chunk * N_ + row0 + tid] = C1;
    }
}

// ---------------- Phase 2: merge 4 chunk-partials + exact verify ----
// Uses k_pre's (mu, inv, A): only ONE f64 reduce chain (the dot) remains.
// Ambiguous rows enqueue to slowL for the balanced k_slow dispatch.
__global__ void k_phase2(const float* __restrict__ x, const float* __restrict__ gam,
                         const float* __restrict__ bet, const float* __restrict__ w,
                         const double* __restrict__ Bw, const float* __restrict__ pq,
                         const float2* __restrict__ muiv, const double* __restrict__ Ar,
                         double* __restrict__ sampled, int* __restrict__ idxf,
                         unsigned* __restrict__ slowC, int* __restrict__ slowL) {
    int lane = threadIdx.x & 63, wv = threadIdx.x >> 6;
    int n = blockIdx.x * 4 + wv;
    const float* pm1 = pq;
    const float* pm2 = pq + 4 * N_;
    const int*   pc1 = (const int*)pq + 8 * N_;
    float M1 = 3e38f, M2 = 3e38f; int C1 = 0x7fffffff;
#pragma unroll
    for (int c = 0; c < 4; c++) {
        float m1 = pm1[c * N_ + n], m2 = pm2[c * N_ + n]; int cc = pc1[c * N_ + n];
        if (m1 < M1 || (m1 == M1 && cc < C1)) {
            M2 = (M1 < m2) ? M1 : m2; M1 = m1; C1 = cc;
        } else {
            M2 = (m1 < M2) ? m1 : M2;
        }
    }
    if (M2 - M1 <= MARGIN) {
        if (lane == 0) { unsigned p = atomicAdd(slowC, 1u); slowL[p] = n; }
        return;
    }
    float2 mi = muiv[n];
    double mu = mi.x, inv = mi.y;
    double A = Ar[n];
    const float* row = x + (size_t)n * D_;
    const float* wr_ = w + (size_t)C1 * D_;
    double ss = 0.0;
#pragma unroll
    for (int i = 0; i < 4; i++) {
        int d = lane + 64 * i;
        double f = ((double)row[d] - mu) * inv * (double)gam[d] + (double)bet[d];
        ss += f * (double)wr_[d];
    }
    for (int m = 32; m > 0; m >>= 1) ss += __shfl_xor(ss, m, 64);
    if (lane == 0) { sampled[n] = (A + Bw[C1]) - 2.0 * ss; idxf[n] = C1; }
}

// ---------------- Slow rows: exact f64 full scan, lanes-over-codes -------------
// Block-per-row grid-stride, 256 thr: thread owns 4 codes (balanced), f64
// feats in LDS broadcast. Uses k_pre's (mu, inv, A): no stat reduce chains.
__launch_bounds__(256)
__global__ void k_slow(const float* __restrict__ x, const float* __restrict__ gam,
                       const float* __restrict__ bet, const float* __restrict__ w,
                       const double* __restrict__ Bw,
                       const float2* __restrict__ muiv, const double* __restrict__ Ar,
                       const int* __restrict__ slowL, const unsigned* __restrict__ slowC,
                       double* __restrict__ sampled, int* __restrict__ idxf) {
    __shared__ double sf[256];
    __shared__ double bmW[4];
    __shared__ int    bcW[4];
    int tid = threadIdx.x, lane = tid & 63, wv = tid >> 6;
    int cnt = (int)*slowC;
    for (int it = blockIdx.x; it < cnt; it += gridDim.x) {
        int n = slowL[it];
        float2 mi = muiv[n];
        double mu = mi.x, inv = mi.y;
        double A = Ar[n];
        double f = ((double)x[(size_t)n * D_ + tid] - mu) * inv
                   * (double)gam[tid] + (double)bet[tid];
        sf[tid] = f;
        __syncthreads();

        double bm = 1.0e300; int bc = 0x7fffffff;
        for (int r = 0; r < 4; r++) {
            int cc = r * 256 + wv * 64 + lane;
            const float* wr = w + (size_t)cc * D_;
            double acc = 0.0;
#pragma unroll 8
            for (int d4 = 0; d4 < 64; d4++) {
                float4 w4 = *(const float4*)(wr + d4 * 4);
                acc += sf[d4 * 4] * (double)w4.x + sf[d4 * 4 + 1] * (double)w4.y
                     + sf[d4 * 4 + 2] * (double)w4.z + sf[d4 * 4 + 3] * (double)w4.w;
            }
            double dist = (A + Bw[cc]) - 2.0 * acc;
            if (dist < bm) { bm = dist; bc = cc; }   // r ascending => lowest idx on tie
        }
        for (int m = 32; m > 0; m >>= 1) {
            double om = __shfl_xor(bm, m, 64);
            int    oc = __shfl_xor(bc, m, 64);
            if (om < bm || (om == bm && oc < bc)) { bm = om; bc = oc; }
        }
        if (lane == 0) { bmW[wv] = bm; bcW[wv] = bc; }
        __syncthreads();
        if (tid == 0) {
            double M = bmW[0]; int C = bcW[0];
            for (int i = 1; i < 4; i++)
                if (bmW[i] < M || (bmW[i] == M && bcW[i] < C)) { M = bmW[i]; C = bcW[i]; }
            sampled[n] = M; idxf[n] = C;
        }
        __syncthreads();
    }
}

// ---------------- stable argsort via parallel ranking -------------
// rank_i = #{j: v_j < v_i} + #{j<i: v_j == v_i}  (== stable argsort position)
// NOTE: enc[base+rank] = idxf[i] with i ROW-LOCAL (no base) -- faithful
// reproduction of the reference's flat-index bug.
__launch_bounds__(256)
__global__ void k_rank(const double* __restrict__ sampled, const int* __restrict__ idxf,
                       int* __restrict__ enc) {
    __shared__ double val[1024];
    int b = blockIdx.x >> 2;            // batch row
    int q = blockIdx.x & 3;             // quarter of the row
    int t = threadIdx.x;
    size_t base = (size_t)b * S_;
#pragma unroll
    for (int e = 0; e < 4; e++)
        val[t + e * 256] = sampled[base + t + e * 256];
    __syncthreads();
    int i = q * 256 + t;                // row-local element index
    double vi = val[i];
    int rank = 0;
#pragma unroll 8
    for (int j = 0; j < 1024; j++) {
        double vj = val[j];
        rank += (vj < vi) || (vj == vi && j < i);
    }
    enc[base + rank] = idxf[i];         // faithful reference flat-index bug
}

// ---------------- gather: quantized out, idx out, counts, per-row loss -------------
__global__ void k_gather(const float* __restrict__ x, const float* __restrict__ w,
                         const int* __restrict__ enc, float* __restrict__ out,
                         unsigned* __restrict__ cnt, double* __restrict__ lossP) {
    int lane = threadIdx.x & 63, wv = threadIdx.x >> 6;
    int n = blockIdx.x * 4 + wv;
    int e = enc[n];
    const float4 q4 = ((const float4*)(w + (size_t)e * D_))[lane];
    const float4 x4 = ((const float4*)(x + (size_t)n * D_))[lane];
    ((float4*)(out + O_Q + (size_t)n * D_))[lane] = q4;
    double d0 = (double)q4.x - (double)x4.x;
    double d1 = (double)q4.y - (double)x4.y;
    double d2 = (double)q4.z - (double)x4.z;
    double d3 = (double)q4.w - (double)x4.w;
    double ls = d0 * d0 + d1 * d1 + d2 * d2 + d3 * d3;
    for (int m = 32; m > 0; m >>= 1) ls += __shfl_xor(ls, m, 64);
    if (lane == 0) {
        lossP[n] = ls;
        out[O_IDX + n] = (float)e;
        atomicAdd(&cnt[e], 1u);
    }
}

// ---------------- fused CSR build: scan -> coff; scatter via LDS cursors; ntot ----
// 1 block x 1024 thr. Within-code order is race-nondeterministic exactly like
// the old global-atomic scatter.
__launch_bounds__(1024)
__global__ void k_scansc(const unsigned* __restrict__ cnt, const float* __restrict__ ema_cs,
                         const int* __restrict__ enc, int* __restrict__ coff,
                         int* __restrict__ rowl, double* __restrict__ ntotP) {
    __shared__ int tmp[1024];
    __shared__ int curL[1024];
    __shared__ double redn[16];
    int t = threadIdx.x;
    int my = (int)cnt[t];
    tmp[t] = my;
    double part = (double)(0.99f * ema_cs[t] + 0.01f * (float)my);
    __syncthreads();
    for (int off = 1; off < 1024; off <<= 1) {
        int v = (t >= off) ? tmp[t - off] : 0;
        __syncthreads();
        tmp[t] += v;
        __syncthreads();
    }
    int excl = tmp[t] - my;
    coff[t] = excl;
    curL[t] = excl;
    for (int m = 32; m > 0; m >>= 1) part += __shfl_xor(part, m, 64);
    if ((t & 63) == 0) redn[t >> 6] = part;
    __syncthreads();
    if (t == 0) {
        double s = 0.0;
        for (int i = 0; i < 16; i++) s += redn[i];
        *ntotP = s;
    }
    // scatter: 32 strided passes over enc
    for (int it = 0; it < 32; it++) {
        int i = it * 1024 + t;
        int e = enc[i];
        int p = atomicAdd(&curL[e], 1);
        rowl[p] = i;
    }
}

// ---------------- post: dw via CSR row-list + new_weight + stats -------------
// ntot precomputed by k_scansc; 8-deep row pipeline for latency hiding.
__launch_bounds__(256)
__global__ void k_post(const unsigned* __restrict__ cnt, const float* __restrict__ ema_cs,
                       const double* __restrict__ lossP,
                       const int* __restrict__ coff, const int* __restrict__ rowl,
                       const float* __restrict__ x, const float* __restrict__ ema_w,
                       const double* __restrict__ ntotP, float* __restrict__ out) {
    __shared__ double redd[24];
    int tid = threadIdx.x;
    double ntot = *ntotP;

    if (blockIdx.x < K_) {
        int k = blockIdx.x;
        float cs0 = 0.99f * ema_cs[k] + 0.01f * (float)cnt[k];
        double csf = ((double)cs0 + 1e-5) / (ntot + 1024.0 * 1e-5) * ntot;
        int base = coff[k];
        int c = (int)cnt[k];
        float acc = 0.0f;
        int j = 0;
        for (; j + 8 <= c; j += 8) {
            int r[8];
#pragma unroll
            for (int u = 0; u < 8; u++) r[u] = rowl[base + j + u];
            float v[8];
#pragma unroll
            for (int u = 0; u < 8; u++) v[u] = x[(size_t)r[u] * D_ + tid];
#pragma unroll
            for (int u = 0; u < 8; u++) acc += v[u];
        }
        for (; j < c; j++) acc += x[(size_t)rowl[base + j] * D_ + tid];
        size_t idx = (size_t)k * D_ + tid;
        float ne = 0.99f * ema_w[idx] + 0.01f * acc;
        out[O_NEW + idx] = ne;
        out[O_NW + idx] = ne / (float)csf;
    } else {
        // stats block
        for (int i = tid; i < K_; i += 256) {
            float cs0 = 0.99f * ema_cs[i] + 0.01f * (float)cnt[i];
            double c2 = ((double)cs0 + 1e-5) / (ntot + 1024.0 * 1e-5) * ntot;
            out[O_NCS + i] = (float)c2;
        }
        double ent = 0.0;
        for (int i = tid; i < K_; i += 256) {
            double p = (double)cnt[i] / 32768.0;
            ent += -p * log(p + 1e-10);
        }
        for (int m = 32; m > 0; m >>= 1) ent += __shfl_xor(ent, m, 64);
        if ((tid & 63) == 0) redd[8 + (tid >> 6)] = ent;
        double ls = 0.0;
        for (int i = tid; i < N_; i += 256) ls += lossP[i];
        for (int m = 32; m > 0; m >>= 1) ls += __shfl_xor(ls, m, 64);
        if ((tid & 63) == 0) redd[16 + (tid >> 6)] = ls;
        __syncthreads();
        if (tid == 0) {
            double e = redd[8] + redd[9] + redd[10] + redd[11];
            double l = redd[16] + redd[17] + redd[18] + redd[19];
            out[O_PERP] = (float)exp(e);
            out[O_LOSS] = (float)(1.25 * l / 8388608.0);
        }
    }
}

extern "C" void kernel_launch(void* const* d_in, const int* in_sizes, int n_in,
                              void* d_out, int out_size, void* d_ws, size_t ws_size,
                              hipStream_t stream) {
    (void)in_sizes; (void)n_in; (void)out_size; (void)ws_size;
    const float* x      = (const float*)d_in[0];
    const float* w      = (const float*)d_in[1];
    const float* ema_w  = (const float*)d_in[2];
    const float* ema_cs = (const float*)d_in[3];
    const float* g      = (const float*)d_in[4];
    const float* bt     = (const float*)d_in[5];
    float* out = (float*)d_out;
    char* ws = (char*)d_ws;

    _Float16* fh = (_Float16*)(ws + OFF_FH);
    _Float16* wh = (_Float16*)(ws + OFF_WH);
    double* Bw   = (double*)(ws + OFF_BW);
    float*  Bwf  = (float*)(ws + OFF_BWF);
    double* samp = (double*)(ws + OFF_SAMP);
    int*    idxf = (int*)(ws + OFF_IDXF);
    int*    enc  = (int*)(ws + OFF_ENC);
    unsigned* cnt = (unsigned*)(ws + OFF_CNT);
    unsigned* slowC = (unsigned*)(ws + OFF_SLOWC);
    int*    slowL = (int*)(ws + OFF_SLOWL);
    double* lossP = (double*)(ws + OFF_LOSSP);
    int*    coff  = (int*)(ws + OFF_COFF);
    int*    rowl  = (int*)(ws + OFF_ROWL);
    float2* muiv  = (float2*)(ws + OFF_MUIV);
    double* Ar    = (double*)(ws + OFF_AR);
    double* ntotP = (double*)(ws + OFF_NTOT);

    k_pre<<<N_ / 4 + K_ / 4 + 1, 256, 0, stream>>>(x, g, bt, fh, w, Bw, Bwf, wh,
                                                   muiv, Ar, cnt, slowC);
    k_phase1<<<1024, 512, 0, stream>>>(fh, wh, Bwf, out);  // partials in out-Q (dead region)
    k_phase2<<<N_ / 4, 256, 0, stream>>>(x, g, bt, w, Bw, out, muiv, Ar,
                                         samp, idxf, slowC, slowL);
    k_slow<<<2048, 256, 0, stream>>>(x, g, bt, w, Bw, muiv, Ar, slowL, slowC, samp, idxf);
    k_rank<<<B_ * 4, 256, 0, stream>>>(samp, idxf, enc);
    k_gather<<<N_ / 4, 256, 0, stream>>>(x, w, enc, out, cnt, lossP);
    k_scansc<<<1, 1024, 0, stream>>>(cnt, ema_cs, enc, coff, rowl, ntotP);
    k_post<<<K_ + 1, 256, 0, stream>>>(cnt, ema_cs, lossP, coff, rowl, x, ema_w,
                                       ntotP, out);
}

// Round 11
// 275.117 us; speedup vs baseline: 1.3703x; 1.0592x over previous
//
#include <hip/hip_runtime.h>
#include <cmath>

#define B_ 32
#define S_ 1024
#define D_ 256
#define K_ 1024
#define N_ (B_*S_)

// ---- output layout (float elements) ----
#define O_Q     0
#define O_LOSS  8388608
#define O_PERP  8388609
#define O_IDX   8388610
#define O_NW    8421378
#define O_NEW   8683522
#define O_NCS   8945666

// ---- workspace layout (bytes) ----
#define OFF_FH    0ull          // N*256*2 = 16777216 (f16 feats)
#define OFF_WH    16777216ull   // K*256*2 = 524288  (f16 weights)
#define OFF_BW    17301504ull   // K*8
#define OFF_BWF   17309696ull   // K*4
#define OFF_SAMP  17313792ull   // N*8
#define OFF_IDXF  17575936ull   // N*4
#define OFF_ENC   17707008ull   // N*4
#define OFF_CNT   17838080ull   // K*4 (zeroed by k_pre tail block)
#define OFF_SLOWC 17842176ull   // 64  (zeroed by k_pre tail block)
#define OFF_SLOWL 17842240ull   // N*4
#define OFF_LOSSP 17973312ull   // N*8
#define OFF_COFF  18235456ull   // K*4  CSR offsets
#define OFF_CUR   18239552ull   // K*4  scatter cursors
#define OFF_ROWL  18243648ull   // N*4  CSR row list
#define OFF_MUIV  18374720ull   // N*8  (f32 mu, f32 inv) per row
#define OFF_AR    18636864ull   // N*8  f64 ||f||^2 per row
#define OFF_NTOT  18899008ull   // 8    f64 ntot

#define MARGIN 4e-5f

typedef _Float16 f16x8 __attribute__((ext_vector_type(8)));
typedef _Float16 f16x4 __attribute__((ext_vector_type(4)));
typedef float    f32x4 __attribute__((ext_vector_type(4)));

// offset arg must be a literal at Sema time -> fold k-offset into gp instead.
#define GL16(gp, lp) __builtin_amdgcn_global_load_lds( \
    (const __attribute__((address_space(1))) unsigned int*)(const void*)(gp), \
    (__attribute__((address_space(3))) unsigned int*)(void*)(lp), 16, 0, 0)

// ---------------- fused: LN -> f16 feats + (mu,inv,A) | ||w||^2 + f16 w ----
// f32 LN math; stores per-row (mu, inv) f32 and A=||f||^2 (f64-accumulated)
// so phase2/slow skip the stat reduce chains. Tail block zeroes cnt+slowC.
__global__ void k_pre(const float* __restrict__ x, const float* __restrict__ gam,
                      const float* __restrict__ bet, _Float16* __restrict__ fh,
                      const float* __restrict__ w, double* __restrict__ Bw,
                      float* __restrict__ Bwf, _Float16* __restrict__ wh,
                      float2* __restrict__ muiv, double* __restrict__ Ar,
                      unsigned* __restrict__ cnt, unsigned* __restrict__ slowC) {
    int lane = threadIdx.x & 63, wv = threadIdx.x >> 6;
    if (blockIdx.x < N_ / 4) {
        int n = blockIdx.x * 4 + wv;
        const float4 xv = ((const float4*)(x + (size_t)n * D_))[lane];
        const float4 gv = ((const float4*)gam)[lane];
        const float4 bv = ((const float4*)bet)[lane];
        float s = xv.x + xv.y + xv.z + xv.w;
        for (int m = 32; m > 0; m >>= 1) s += __shfl_xor(s, m, 64);
        float mu = s * (1.0f / 256.0f);
        float c0 = xv.x - mu, c1 = xv.y - mu, c2 = xv.z - mu, c3 = xv.w - mu;
        float vs = c0 * c0 + c1 * c1 + c2 * c2 + c3 * c3;
        for (int m = 32; m > 0; m >>= 1) vs += __shfl_xor(vs, m, 64);
        float inv = 1.0f / sqrtf(vs * (1.0f / 256.0f) + 1e-5f);
        float f0 = c0 * inv * gv.x + bv.x;
        float f1 = c1 * inv * gv.y + bv.y;
        float f2 = c2 * inv * gv.z + bv.z;
        float f3 = c3 * inv * gv.w + bv.w;
        double a = (double)f0 * f0 + (double)f1 * f1
                 + (double)f2 * f2 + (double)f3 * f3;
        for (int m = 32; m > 0; m >>= 1) a += __shfl_xor(a, m, 64);
        f16x4 o;
        o[0] = (_Float16)f0; o[1] = (_Float16)f1;
        o[2] = (_Float16)f2; o[3] = (_Float16)f3;
        *(f16x4*)&fh[(size_t)n * D_ + lane * 4] = o;
        if (lane == 0) { muiv[n] = make_float2(mu, inv); Ar[n] = a; }
    } else if (blockIdx.x < N_ / 4 + K_ / 4) {
        int k = (blockIdx.x - N_ / 4) * 4 + wv;
        const float4 v = ((const float4*)(w + (size_t)k * D_))[lane];
        double s = (double)v.x * v.x + (double)v.y * v.y
                 + (double)v.z * v.z + (double)v.w * v.w;
        for (int m = 32; m > 0; m >>= 1) s += __shfl_xor(s, m, 64);
        f16x4 o;
        o[0] = (_Float16)v.x; o[1] = (_Float16)v.y;
        o[2] = (_Float16)v.z; o[3] = (_Float16)v.w;
        *(f16x4*)&wh[(size_t)k * D_ + lane * 4] = o;
        if (lane == 0) { Bw[k] = s; Bwf[k] = (float)s; }
    } else {
        // zero cnt (K u32) + slowC
        int t = threadIdx.x;
#pragma unroll
        for (int i = 0; i < 4; i++) cnt[t + i * 256] = 0u;
        if (t == 0) *slowC = 0u;
    }
}

// ---------------- Phase 1: f16 MFMA GEMM + fused top-2 -------------
// 1024 blocks x 512 thr (8 waves). Block = 128 rows x 256 codes;
// wave (wr,wc) owns a 64x64 sub-tile; acc = 16 f32x4 = 64 regs/wave.
// OPERAND-SWAPPED MFMA; counted vmcnt(3) 3-buffer schedule (R4 winner).
// NEW (T2, rule #21): LDS slot-XOR swizzle. global_load_lds writes linearly,
// so the GLOBAL source column-slot is pre-swizzled per lane
// (slot' = slot ^ ((row>>1)&3)) and the ds_read applies the same XOR
// (gx = g ^ ((l15>>1)&3)). Pre-swizzle each bank quad served 16 lanes
// (8-deep stack, 2x LDS time); post-swizzle 8 lanes/quad = the 8-cyc
// minimum. Predicted: SQ_LDS_BANK_CONFLICT 2.29M -> ~0, dur ~40 -> ~28.
__launch_bounds__(512, 4)
__global__ void k_phase1(const _Float16* __restrict__ fh, const _Float16* __restrict__ wh,
                         const float* __restrict__ Bwf, float* __restrict__ pq) {
    __shared__ __align__(16) _Float16 sA[3][128][32];   // 24 KB
    __shared__ __align__(16) _Float16 sB[3][256][32];   // 48 KB

    const int tid = threadIdx.x;
    const int lane = tid & 63;
    const int w = tid >> 6;        // wave 0..7
    const int wr = w >> 2;         // row half 0..1 (64 rows)
    const int wc = w & 3;          // col quarter 0..3 (64 codes)
    const int l15 = lane & 15;
    const int g = lane >> 4;       // 0..3
    const int gx = g ^ ((l15 >> 1) & 3);   // swizzled read slot (const per lane)
    const int id = blockIdx.x;
    const int grp = (id & 7) * 32 + (id >> 5);       // 0..255
    const int chunk = (id >> 3) & 3;
    const int row0 = grp * 128;
    const int c0 = chunk * 256;

    // staging: 24 GL16 loads cover A(8KB)+B(16KB) per epoch; wave w owns
    // loads li = 3w..3w+2. li<8 -> A rows li*16, li>=8 -> B rows (li-8)*16.
    // Global col-slot pre-swizzled so LDS slot (r,cb) holds global (r, cb^f(r)).
    const int srow = lane >> 2;
    const int scol = (((lane & 3) ^ ((srow >> 1) & 3)) * 8);
    const _Float16* gp[3];
    int lrow[3]; int isA[3];
#pragma unroll
    for (int j = 0; j < 3; j++) {
        int li = w * 3 + j;
        if (li < 8) {
            isA[j] = 1; lrow[j] = li * 16;
            gp[j] = fh + (size_t)(row0 + li * 16 + srow) * 256 + scol;
        } else {
            isA[j] = 0; lrow[j] = (li - 8) * 16;
            gp[j] = wh + (size_t)(c0 + (li - 8) * 16 + srow) * 256 + scol;
        }
    }

    // acc[cb][rb]: cb = code block (16 codes), rb = row block (16 rows)
    f32x4 acc[4][4];
#pragma unroll
    for (int a = 0; a < 4; a++)
#pragma unroll
        for (int b = 0; b < 4; b++) acc[a][b] = (f32x4){0.f, 0.f, 0.f, 0.f};

#define STAGE(bi, kk) do { \
    const int eoff_ = (kk) * 32; \
    _Pragma("unroll") \
    for (int j_ = 0; j_ < 3; j_++) { \
        if (isA[j_]) GL16(gp[j_] + eoff_, &sA[bi][lrow[j_]][0]); \
        else         GL16(gp[j_] + eoff_, &sB[bi][lrow[j_]][0]); \
    } \
} while (0)

    // prologue: stage k-steps 0 and 1; wait only this wave's oldest 3 (buf0).
    STAGE(0, 0);
    STAGE(1, 1);
    asm volatile("s_waitcnt vmcnt(3)" ::: "memory");
    __builtin_amdgcn_s_barrier();
    __builtin_amdgcn_sched_barrier(0);

#pragma unroll
    for (int ks = 0; ks < 8; ks++) {
        const int cur = ks % 3;
        if (ks < 6) STAGE((ks + 2) % 3, ks + 2);   // 3 new loads in flight/wave

        f16x8 cfr[4];   // code fragments (A-operand after swap), swizzled read
#pragma unroll
        for (int cb = 0; cb < 4; cb++)
            cfr[cb] = *(const f16x8*)&sB[cur][wc * 64 + cb * 16 + l15][gx * 8];
        __builtin_amdgcn_s_setprio(1);
#pragma unroll
        for (int rb = 0; rb < 4; rb++) {
            f16x8 rf = *(const f16x8*)&sA[cur][wr * 64 + rb * 16 + l15][gx * 8];
#pragma unroll
            for (int cb = 0; cb < 4; cb++)
                acc[cb][rb] = __builtin_amdgcn_mfma_f32_16x16x32_f16(
                    cfr[cb], rf, acc[cb][rb], 0, 0, 0);
        }
        __builtin_amdgcn_s_setprio(0);
        __builtin_amdgcn_sched_barrier(0);

        // end of epoch: wait for NEXT buffer's loads only (issued last epoch),
        // leaving this epoch's 3 prefetches in flight across the barrier.
        if (ks < 6)       asm volatile("s_waitcnt vmcnt(3)" ::: "memory");
        else if (ks == 6) asm volatile("s_waitcnt vmcnt(0)" ::: "memory");
        if (ks < 7) {
            __builtin_amdgcn_s_barrier();
            __builtin_amdgcn_sched_barrier(0);
        }
    }
#undef STAGE
    __syncthreads();

    // per-lane ||w||^2 for its 16 codes: code = c0 + wc*64 + cb*16 + g*4 + r
    float bwv[4][4];
#pragma unroll
    for (int cb = 0; cb < 4; cb++)
#pragma unroll
        for (int r = 0; r < 4; r++)
            bwv[cb][r] = Bwf[c0 + wc * 64 + cb * 16 + g * 4 + r];

    // red: 128 rows x 4 wc-quadrant triples (m1,m2,c1) = 6 KB in sA[0]
    float* red = (float*)&sA[0][0][0];
#pragma unroll
    for (int rb = 0; rb < 4; rb++) {
        float m1 = 3e38f, m2 = 3e38f; int c1 = 0x7fffffff;
#pragma unroll
        for (int cb = 0; cb < 4; cb++) {
#pragma unroll
            for (int r = 0; r < 4; r++) {
                float sv = fmaf(-2.0f, acc[cb][rb][r], bwv[cb][r]);
                int c = c0 + wc * 64 + cb * 16 + g * 4 + r;
                if (sv < m1 || (sv == m1 && c < c1)) { m2 = m1; m1 = sv; c1 = c; }
                else if (sv < m2) m2 = sv;
            }
        }
        // reduce across the 4 g-groups (lanes stride 16)
#pragma unroll
        for (int msk = 16; msk <= 32; msk <<= 1) {
            float om1 = __shfl_xor(m1, msk, 64);
            float om2 = __shfl_xor(m2, msk, 64);
            int   oc  = __shfl_xor(c1, msk, 64);
            if (om1 < m1 || (om1 == m1 && oc < c1)) {
                m2 = (m1 < om2) ? m1 : om2; m1 = om1; c1 = oc;
            } else {
                m2 = (om1 < m2) ? om1 : m2;
            }
        }
        if (lane < 16) {
            int rl = wr * 64 + rb * 16 + l15;
            int base = (rl * 4 + wc) * 3;
            red[base] = m1; red[base + 1] = m2; ((int*)red)[base + 2] = c1;
        }
    }
    __syncthreads();
    if (tid < 128) {
        float M1 = 3e38f, M2 = 3e38f; int C1 = 0x7fffffff;
        for (int q = 0; q < 4; q++) {
            int base = (tid * 4 + q) * 3;
            float m1 = red[base], m2 = red[base + 1]; int c = ((int*)red)[base + 2];
            if (m1 < M1 || (m1 == M1 && c < C1)) {
                M2 = (M1 < m2) ? M1 : m2; M1 = m1; C1 = c;
            } else {
                M2 = (m1 < M2) ? m1 : M2;
            }
        }
        pq[chunk * N_ + row0 + tid] = M1;
        pq[4 * N_ + chunk * N_ + row0 + tid] = M2;
        ((int*)pq)[8 * N_ + chunk * N_ + row0 + tid] = C1;
    }
}

// ---------------- Phase 2: merge 4 chunk-partials + exact verify ----
// Uses k_pre's (mu, inv, A): only ONE f64 reduce chain (the dot) remains.
// Ambiguous rows enqueue to slowL for the balanced k_slow dispatch.
__global__ void k_phase2(const float* __restrict__ x, const float* __restrict__ gam,
                         const float* __restrict__ bet, const float* __restrict__ w,
                         const double* __restrict__ Bw, const float* __restrict__ pq,
                         const float2* __restrict__ muiv, const double* __restrict__ Ar,
                         double* __restrict__ sampled, int* __restrict__ idxf,
                         unsigned* __restrict__ slowC, int* __restrict__ slowL) {
    int lane = threadIdx.x & 63, wv = threadIdx.x >> 6;
    int n = blockIdx.x * 4 + wv;
    const float* pm1 = pq;
    const float* pm2 = pq + 4 * N_;
    const int*   pc1 = (const int*)pq + 8 * N_;
    float M1 = 3e38f, M2 = 3e38f; int C1 = 0x7fffffff;
#pragma unroll
    for (int c = 0; c < 4; c++) {
        float m1 = pm1[c * N_ + n], m2 = pm2[c * N_ + n]; int cc = pc1[c * N_ + n];
        if (m1 < M1 || (m1 == M1 && cc < C1)) {
            M2 = (M1 < m2) ? M1 : m2; M1 = m1; C1 = cc;
        } else {
            M2 = (m1 < M2) ? m1 : M2;
        }
    }
    if (M2 - M1 <= MARGIN) {
        if (lane == 0) { unsigned p = atomicAdd(slowC, 1u); slowL[p] = n; }
        return;
    }
    float2 mi = muiv[n];
    double mu = mi.x, inv = mi.y;
    double A = Ar[n];
    const float* row = x + (size_t)n * D_;
    const float* wr_ = w + (size_t)C1 * D_;
    double ss = 0.0;
#pragma unroll
    for (int i = 0; i < 4; i++) {
        int d = lane + 64 * i;
        double f = ((double)row[d] - mu) * inv * (double)gam[d] + (double)bet[d];
        ss += f * (double)wr_[d];
    }
    for (int m = 32; m > 0; m >>= 1) ss += __shfl_xor(ss, m, 64);
    if (lane == 0) { sampled[n] = (A + Bw[C1]) - 2.0 * ss; idxf[n] = C1; }
}

// ---------------- Slow rows: exact f64 full scan, lanes-over-codes -------------
// Block-per-row grid-stride, 256 thr: thread owns 4 codes (balanced), f64
// feats in LDS broadcast. Uses k_pre's (mu, inv, A): no stat reduce chains.
__launch_bounds__(256)
__global__ void k_slow(const float* __restrict__ x, const float* __restrict__ gam,
                       const float* __restrict__ bet, const float* __restrict__ w,
                       const double* __restrict__ Bw,
                       const float2* __restrict__ muiv, const double* __restrict__ Ar,
                       const int* __restrict__ slowL, const unsigned* __restrict__ slowC,
                       double* __restrict__ sampled, int* __restrict__ idxf) {
    __shared__ double sf[256];
    __shared__ double bmW[4];
    __shared__ int    bcW[4];
    int tid = threadIdx.x, lane = tid & 63, wv = tid >> 6;
    int cnt = (int)*slowC;
    for (int it = blockIdx.x; it < cnt; it += gridDim.x) {
        int n = slowL[it];
        float2 mi = muiv[n];
        double mu = mi.x, inv = mi.y;
        double A = Ar[n];
        double f = ((double)x[(size_t)n * D_ + tid] - mu) * inv
                   * (double)gam[tid] + (double)bet[tid];
        sf[tid] = f;
        __syncthreads();

        double bm = 1.0e300; int bc = 0x7fffffff;
        for (int r = 0; r < 4; r++) {
            int cc = r * 256 + wv * 64 + lane;
            const float* wr = w + (size_t)cc * D_;
            double acc = 0.0;
#pragma unroll 8
            for (int d4 = 0; d4 < 64; d4++) {
                float4 w4 = *(const float4*)(wr + d4 * 4);
                acc += sf[d4 * 4] * (double)w4.x + sf[d4 * 4 + 1] * (double)w4.y
                     + sf[d4 * 4 + 2] * (double)w4.z + sf[d4 * 4 + 3] * (double)w4.w;
            }
            double dist = (A + Bw[cc]) - 2.0 * acc;
            if (dist < bm) { bm = dist; bc = cc; }   // r ascending => lowest idx on tie
        }
        for (int m = 32; m > 0; m >>= 1) {
            double om = __shfl_xor(bm, m, 64);
            int    oc = __shfl_xor(bc, m, 64);
            if (om < bm || (om == bm && oc < bc)) { bm = om; bc = oc; }
        }
        if (lane == 0) { bmW[wv] = bm; bcW[wv] = bc; }
        __syncthreads();
        if (tid == 0) {
            double M = bmW[0]; int C = bcW[0];
            for (int i = 1; i < 4; i++)
                if (bmW[i] < M || (bmW[i] == M && bcW[i] < C)) { M = bmW[i]; C = bcW[i]; }
            sampled[n] = M; idxf[n] = C;
        }
        __syncthreads();
    }
}

// ---------------- stable argsort via parallel ranking -------------
// rank_i = #{j: v_j < v_i} + #{j<i: v_j == v_i}  (== stable argsort position)
// NOTE: enc[base+rank] = idxf[i] with i ROW-LOCAL (no base) -- faithful
// reproduction of the reference's flat-index bug.
__launch_bounds__(256)
__global__ void k_rank(const double* __restrict__ sampled, const int* __restrict__ idxf,
                       int* __restrict__ enc) {
    __shared__ double val[1024];
    int b = blockIdx.x >> 2;            // batch row
    int q = blockIdx.x & 3;             // quarter of the row
    int t = threadIdx.x;
    size_t base = (size_t)b * S_;
#pragma unroll
    for (int e = 0; e < 4; e++)
        val[t + e * 256] = sampled[base + t + e * 256];
    __syncthreads();
    int i = q * 256 + t;                // row-local element index
    double vi = val[i];
    int rank = 0;
#pragma unroll 8
    for (int j = 0; j < 1024; j++) {
        double vj = val[j];
        rank += (vj < vi) || (vj == vi && j < i);
    }
    enc[base + rank] = idxf[i];         // faithful reference flat-index bug
}

// ---------------- gather: quantized out, idx out, counts, per-row loss -------------
__global__ void k_gather(const float* __restrict__ x, const float* __restrict__ w,
                         const int* __restrict__ enc, float* __restrict__ out,
                         unsigned* __restrict__ cnt, double* __restrict__ lossP) {
    int lane = threadIdx.x & 63, wv = threadIdx.x >> 6;
    int n = blockIdx.x * 4 + wv;
    int e = enc[n];
    const float4 q4 = ((const float4*)(w + (size_t)e * D_))[lane];
    const float4 x4 = ((const float4*)(x + (size_t)n * D_))[lane];
    ((float4*)(out + O_Q + (size_t)n * D_))[lane] = q4;
    double d0 = (double)q4.x - (double)x4.x;
    double d1 = (double)q4.y - (double)x4.y;
    double d2 = (double)q4.z - (double)x4.z;
    double d3 = (double)q4.w - (double)x4.w;
    double ls = d0 * d0 + d1 * d1 + d2 * d2 + d3 * d3;
    for (int m = 32; m > 0; m >>= 1) ls += __shfl_xor(ls, m, 64);
    if (lane == 0) {
        lossP[n] = ls;
        out[O_IDX + n] = (float)e;
        atomicAdd(&cnt[e], 1u);
    }
}

// ---------------- CSR build: exclusive prefix of cnt -> coff, cur; + ntot ----
__launch_bounds__(1024)
__global__ void k_scan(const unsigned* __restrict__ cnt, const float* __restrict__ ema_cs,
                       int* __restrict__ coff, int* __restrict__ cur,
                       double* __restrict__ ntotP) {
    __shared__ int tmp[1024];
    __shared__ double redn[16];
    int t = threadIdx.x;
    int my = (int)cnt[t];
    tmp[t] = my;
    double part = (double)(0.99f * ema_cs[t] + 0.01f * (float)my);
    __syncthreads();
    for (int off = 1; off < 1024; off <<= 1) {
        int v = (t >= off) ? tmp[t - off] : 0;
        __syncthreads();
        tmp[t] += v;
        __syncthreads();
    }
    int excl = tmp[t] - my;
    coff[t] = excl;
    cur[t] = excl;
    for (int m = 32; m > 0; m >>= 1) part += __shfl_xor(part, m, 64);
    if ((t & 63) == 0) redn[t >> 6] = part;
    __syncthreads();
    if (t == 0) {
        double s = 0.0;
        for (int i = 0; i < 16; i++) s += redn[i];
        *ntotP = s;
    }
}

// ---------------- CSR scatter: rowl[coff[e]..] = rows with enc==e -------------
__global__ void k_scatter(const int* __restrict__ enc, int* __restrict__ cur,
                          int* __restrict__ rowl) {
    int n = blockIdx.x * 256 + threadIdx.x;
    int e = enc[n];
    int p = atomicAdd(&cur[e], 1);
    rowl[p] = n;
}

// ---------------- post: dw via CSR row-list + new_weight + stats -------------
// ntot precomputed by k_scan; 8-deep row pipeline for latency hiding.
__launch_bounds__(256)
__global__ void k_post(const unsigned* __restrict__ cnt, const float* __restrict__ ema_cs,
                       const double* __restrict__ lossP,
                       const int* __restrict__ coff, const int* __restrict__ rowl,
                       const float* __restrict__ x, const float* __restrict__ ema_w,
                       const double* __restrict__ ntotP, float* __restrict__ out) {
    __shared__ double redd[24];
    int tid = threadIdx.x;
    double ntot = *ntotP;

    if (blockIdx.x < K_) {
        int k = blockIdx.x;
        float cs0 = 0.99f * ema_cs[k] + 0.01f * (float)cnt[k];
        double csf = ((double)cs0 + 1e-5) / (ntot + 1024.0 * 1e-5) * ntot;
        int base = coff[k];
        int c = (int)cnt[k];
        float acc = 0.0f;
        int j = 0;
        for (; j + 8 <= c; j += 8) {
            int r[8];
#pragma unroll
            for (int u = 0; u < 8; u++) r[u] = rowl[base + j + u];
            float v[8];
#pragma unroll
            for (int u = 0; u < 8; u++) v[u] = x[(size_t)r[u] * D_ + tid];
#pragma unroll
            for (int u = 0; u < 8; u++) acc += v[u];
        }
        for (; j < c; j++) acc += x[(size_t)rowl[base + j] * D_ + tid];
        size_t idx = (size_t)k * D_ + tid;
        float ne = 0.99f * ema_w[idx] + 0.01f * acc;
        out[O_NEW + idx] = ne;
        out[O_NW + idx] = ne / (float)csf;
    } else {
        // stats block
        for (int i = tid; i < K_; i += 256) {
            float cs0 = 0.99f * ema_cs[i] + 0.01f * (float)cnt[i];
            double c2 = ((double)cs0 + 1e-5) / (ntot + 1024.0 * 1e-5) * ntot;
            out[O_NCS + i] = (float)c2;
        }
        double ent = 0.0;
        for (int i = tid; i < K_; i += 256) {
            double p = (double)cnt[i] / 32768.0;
            ent += -p * log(p + 1e-10);
        }
        for (int m = 32; m > 0; m >>= 1) ent += __shfl_xor(ent, m, 64);
        if ((tid & 63) == 0) redd[8 + (tid >> 6)] = ent;
        double ls = 0.0;
        for (int i = tid; i < N_; i += 256) ls += lossP[i];
        for (int m = 32; m > 0; m >>= 1) ls += __shfl_xor(ls, m, 64);
        if ((tid & 63) == 0) redd[16 + (tid >> 6)] = ls;
        __syncthreads();
        if (tid == 0) {
            double e = redd[8] + redd[9] + redd[10] + redd[11];
            double l = redd[16] + redd[17] + redd[18] + redd[19];
            out[O_PERP] = (float)exp(e);
            out[O_LOSS] = (float)(1.25 * l / 8388608.0);
        }
    }
}

extern "C" void kernel_launch(void* const* d_in, const int* in_sizes, int n_in,
                              void* d_out, int out_size, void* d_ws, size_t ws_size,
                              hipStream_t stream) {
    (void)in_sizes; (void)n_in; (void)out_size; (void)ws_size;
    const float* x      = (const float*)d_in[0];
    const float* w      = (const float*)d_in[1];
    const float* ema_w  = (const float*)d_in[2];
    const float* ema_cs = (const float*)d_in[3];
    const float* g      = (const float*)d_in[4];
    const float* bt     = (const float*)d_in[5];
    float* out = (float*)d_out;
    char* ws = (char*)d_ws;

    _Float16* fh = (_Float16*)(ws + OFF_FH);
    _Float16* wh = (_Float16*)(ws + OFF_WH);
    double* Bw   = (double*)(ws + OFF_BW);
    float*  Bwf  = (float*)(ws + OFF_BWF);
    double* samp = (double*)(ws + OFF_SAMP);
    int*    idxf = (int*)(ws + OFF_IDXF);
    int*    enc  = (int*)(ws + OFF_ENC);
    unsigned* cnt = (unsigned*)(ws + OFF_CNT);
    unsigned* slowC = (unsigned*)(ws + OFF_SLOWC);
    int*    slowL = (int*)(ws + OFF_SLOWL);
    double* lossP = (double*)(ws + OFF_LOSSP);
    int*    coff  = (int*)(ws + OFF_COFF);
    int*    cur   = (int*)(ws + OFF_CUR);
    int*    rowl  = (int*)(ws + OFF_ROWL);
    float2* muiv  = (float2*)(ws + OFF_MUIV);
    double* Ar    = (double*)(ws + OFF_AR);
    double* ntotP = (double*)(ws + OFF_NTOT);

    k_pre<<<N_ / 4 + K_ / 4 + 1, 256, 0, stream>>>(x, g, bt, fh, w, Bw, Bwf, wh,
                                                   muiv, Ar, cnt, slowC);
    k_phase1<<<1024, 512, 0, stream>>>(fh, wh, Bwf, out);  // partials in out-Q (dead region)
    k_phase2<<<N_ / 4, 256, 0, stream>>>(x, g, bt, w, Bw, out, muiv, Ar,
                                         samp, idxf, slowC, slowL);
    k_slow<<<2048, 256, 0, stream>>>(x, g, bt, w, Bw, muiv, Ar, slowL, slowC, samp, idxf);
    k_rank<<<B_ * 4, 256, 0, stream>>>(samp, idxf, enc);
    k_gather<<<N_ / 4, 256, 0, stream>>>(x, w, enc, out, cnt, lossP);
    k_scan<<<1, 1024, 0, stream>>>(cnt, ema_cs, coff, cur, ntotP);
    k_scatter<<<N_ / 256, 256, 0, stream>>>(enc, cur, rowl);
    k_post<<<K_ + 1, 256, 0, stream>>>(cnt, ema_cs, lossP, coff, rowl, x, ema_w,
                                       ntotP, out);
}